// Round 2
// baseline (1262.218 us; speedup 1.0000x reference)
//
#include <hip/hip_runtime.h>

// Problem constants (shapes fixed by the reference)
// N=50000, E=600000, IN_CH=128, EDGE_DIM=64, OUT_CH=128
// NOTE: edge_index is int64 in the reference but the harness delivers
// integer inputs as int32 (in_sizes[1] == 2*E int32 elements).

// ---------------------------------------------------------------------------
// K1: fold weights.
//   Wxm[k][c] = sum_j Wx[k][j] * Wm[j][c]          (k<128, top half of Wm)
//   Wem[k][c] = sum_j We[k][j] * Wm[128+j][c]      (k<64,  bottom half of Wm)
//   bf[c]     = bm[c] + sum_j bx[j]*Wm[j][c] + be[j]*Wm[128+j][c]
// ---------------------------------------------------------------------------
__global__ void fuse_weights_kernel(const float* __restrict__ Wx,
                                    const float* __restrict__ bx,
                                    const float* __restrict__ We,
                                    const float* __restrict__ be,
                                    const float* __restrict__ Wm,
                                    const float* __restrict__ bm,
                                    float* __restrict__ Wxm,
                                    float* __restrict__ Wem,
                                    float* __restrict__ bf) {
    int idx = blockIdx.x * blockDim.x + threadIdx.x;
    if (idx < 128 * 128) {
        int r = idx >> 7, c = idx & 127;
        float acc = 0.f;
        #pragma unroll 8
        for (int j = 0; j < 128; ++j) acc += Wx[r * 128 + j] * Wm[j * 128 + c];
        Wxm[idx] = acc;
    } else if (idx < 128 * 128 + 64 * 128) {
        int t = idx - 128 * 128;
        int r = t >> 7, c = t & 127;
        float acc = 0.f;
        #pragma unroll 8
        for (int j = 0; j < 128; ++j) acc += We[r * 128 + j] * Wm[(128 + j) * 128 + c];
        Wem[t] = acc;
    } else if (idx < 128 * 128 + 64 * 128 + 128) {
        int c = idx - (128 * 128 + 64 * 128);
        float acc = bm[c];
        #pragma unroll 8
        for (int j = 0; j < 128; ++j)
            acc += bx[j] * Wm[j * 128 + c] + be[j] * Wm[(128 + j) * 128 + c];
        bf[c] = acc;
    }
}

// ---------------------------------------------------------------------------
// K2: u[n][c] = sum_k x[n][k] * Wxm[k][c] + bf[c]
// Tile: 32 nodes x 128 ch, 256 threads, 4x4 per thread, K=128 in 2 chunks.
// LDS: xs 16KB + ws 32KB = 48KB.
// ---------------------------------------------------------------------------
__global__ __launch_bounds__(256) void node_gemm_kernel(
        const float* __restrict__ x, const float* __restrict__ Wxm,
        const float* __restrict__ bf, float* __restrict__ u, int nNodes) {
    __shared__ __align__(16) float xs[32][128];   // 16 KB
    __shared__ __align__(16) float ws[64][128];   // 32 KB

    int tid = threadIdx.x;
    int n0 = blockIdx.x * 32;

    // stage x tile (row-major): 4096 floats = 1024 float4, 4 per thread
    const float4* x4 = (const float4*)x;
    #pragma unroll
    for (int i = 0; i < 4; ++i) {
        int li = tid + i * 256;            // 0..1023
        int r = li >> 5, c4 = li & 31;     // r<32 node, c4<32 float4-col
        int n = n0 + r;
        float4 v = make_float4(0.f, 0.f, 0.f, 0.f);
        if (n < nNodes) v = x4[(size_t)n * 32 + c4];
        *((float4*)&xs[r][c4 * 4]) = v;
    }

    int cg = tid & 31, ig = tid >> 5;      // cg<32 (c0=4*cg), ig<8 (i0=4*ig)
    int c0 = cg * 4, i0 = ig * 4;
    float acc[4][4] = {};

    for (int kc = 0; kc < 2; ++kc) {
        __syncthreads();
        // stage Wxm rows [kc*64, kc*64+64): 8192 floats = 2048 float4, 8/thread
        const float4* w4 = (const float4*)(Wxm + kc * 64 * 128);
        #pragma unroll
        for (int i = 0; i < 8; ++i) {
            int li = tid + i * 256;
            ((float4*)ws)[li] = w4[li];
        }
        __syncthreads();
        #pragma unroll 4
        for (int k = 0; k < 64; ++k) {
            float4 wv = *((const float4*)&ws[k][c0]);
            int kk = kc * 64 + k;
            float xv[4];
            xv[0] = xs[i0 + 0][kk];
            xv[1] = xs[i0 + 1][kk];
            xv[2] = xs[i0 + 2][kk];
            xv[3] = xs[i0 + 3][kk];
            #pragma unroll
            for (int a = 0; a < 4; ++a) {
                acc[a][0] += xv[a] * wv.x;
                acc[a][1] += xv[a] * wv.y;
                acc[a][2] += xv[a] * wv.z;
                acc[a][3] += xv[a] * wv.w;
            }
        }
    }

    float4 bfv = ((const float4*)bf)[cg];
    #pragma unroll
    for (int a = 0; a < 4; ++a) {
        int n = n0 + i0 + a;
        if (n < nNodes) {
            float4 o;
            o.x = acc[a][0] + bfv.x;
            o.y = acc[a][1] + bfv.y;
            o.z = acc[a][2] + bfv.z;
            o.w = acc[a][3] + bfv.w;
            *((float4*)(u + (size_t)n * 128 + c0)) = o;
        }
    }
}

// ---------------------------------------------------------------------------
// K3: per-edge  t = edge_attr[e] @ Wem ;  msg = leaky_relu(u[src]+t)
//     atomicAdd into out[dst].
// Tile: 64 edges x 128 ch, 512 threads, 4x4 per thread, K=64.
// LDS: eas 16KB + ws 32KB = 48KB -> 3 blocks/CU.
// ---------------------------------------------------------------------------
__global__ __launch_bounds__(512) void edge_kernel(
        const float* __restrict__ ea, const int* __restrict__ ei,
        const float* __restrict__ Wem, const float* __restrict__ u,
        float* __restrict__ out, int E) {
    __shared__ __align__(16) float eas[64][64];   // 16 KB
    __shared__ __align__(16) float ws[64][128];   // 32 KB

    int tid = threadIdx.x;
    int e0 = blockIdx.x * 64;

    // stage Wem: 8192 floats = 2048 float4, 4 per thread
    #pragma unroll
    for (int i = 0; i < 4; ++i)
        ((float4*)ws)[tid + i * 512] = ((const float4*)Wem)[tid + i * 512];

    // stage edge_attr tile: 4096 floats = 1024 float4, 2 per thread
    const float4* ea4 = (const float4*)ea;
    #pragma unroll
    for (int i = 0; i < 2; ++i) {
        int li = tid + i * 512;            // 0..1023
        int r = li >> 4, c4 = li & 15;     // r<64 edge, c4<16
        int e = e0 + r;
        float4 v = make_float4(0.f, 0.f, 0.f, 0.f);
        if (e < E) v = ea4[(size_t)e * 16 + c4];
        *((float4*)&eas[r][c4 * 4]) = v;
    }
    __syncthreads();

    int cg = tid & 31, ig = tid >> 5;      // cg<32, ig<16
    int c0 = cg * 4, i0 = ig * 4;
    float acc[4][4] = {};

    #pragma unroll 4
    for (int k = 0; k < 64; ++k) {
        float4 wv = *((const float4*)&ws[k][c0]);
        float xv[4];
        xv[0] = eas[i0 + 0][k];
        xv[1] = eas[i0 + 1][k];
        xv[2] = eas[i0 + 2][k];
        xv[3] = eas[i0 + 3][k];
        #pragma unroll
        for (int a = 0; a < 4; ++a) {
            acc[a][0] += xv[a] * wv.x;
            acc[a][1] += xv[a] * wv.y;
            acc[a][2] += xv[a] * wv.z;
            acc[a][3] += xv[a] * wv.w;
        }
    }

    const float4* u4 = (const float4*)u;
    #pragma unroll
    for (int a = 0; a < 4; ++a) {
        int e = e0 + i0 + a;
        if (e < E) {
            int s = ei[e];          // src
            int d = ei[E + e];      // dst
            float4 uv = u4[(size_t)s * 32 + cg];
            float m0 = acc[a][0] + uv.x;
            float m1 = acc[a][1] + uv.y;
            float m2 = acc[a][2] + uv.z;
            float m3 = acc[a][3] + uv.w;
            m0 = m0 > 0.f ? m0 : 0.01f * m0;
            m1 = m1 > 0.f ? m1 : 0.01f * m1;
            m2 = m2 > 0.f ? m2 : 0.01f * m2;
            m3 = m3 > 0.f ? m3 : 0.01f * m3;
            float* op = out + (size_t)d * 128 + c0;
            unsafeAtomicAdd(op + 0, m0);
            unsafeAtomicAdd(op + 1, m1);
            unsafeAtomicAdd(op + 2, m2);
            unsafeAtomicAdd(op + 3, m3);
        }
    }
}

// ---------------------------------------------------------------------------
// K4: out = sigmoid(agg) * relu(beta), in place.
// ---------------------------------------------------------------------------
__global__ void finalize_kernel(float* __restrict__ out,
                                const float* __restrict__ beta, int total4) {
    int idx = blockIdx.x * blockDim.x + threadIdx.x;
    if (idx >= total4) return;
    float b = beta[0];
    b = b > 0.f ? b : 0.f;
    float4 v = ((float4*)out)[idx];
    v.x = b / (1.f + __expf(-v.x));
    v.y = b / (1.f + __expf(-v.y));
    v.z = b / (1.f + __expf(-v.z));
    v.w = b / (1.f + __expf(-v.w));
    ((float4*)out)[idx] = v;
}

// ---------------------------------------------------------------------------
extern "C" void kernel_launch(void* const* d_in, const int* in_sizes, int n_in,
                              void* d_out, int out_size, void* d_ws, size_t ws_size,
                              hipStream_t stream) {
    const float* x    = (const float*)d_in[0];
    const int*   ei   = (const int*)d_in[1];     // int64 in ref -> int32 here
    const float* ea   = (const float*)d_in[2];
    const float* Wx   = (const float*)d_in[3];
    const float* bx   = (const float*)d_in[4];
    const float* We   = (const float*)d_in[5];
    const float* be   = (const float*)d_in[6];
    const float* Wm   = (const float*)d_in[7];
    const float* bm   = (const float*)d_in[8];
    const float* beta = (const float*)d_in[9];

    int N = in_sizes[0] / 128;   // 50000
    int E = in_sizes[2] / 64;    // 600000

    float* out = (float*)d_out;

    // workspace layout (16B-aligned offsets)
    char*  ws  = (char*)d_ws;
    float* Wxm = (float*)(ws);                       // 128*128*4 = 65536 B
    float* Wem = (float*)(ws + 65536);               // 64*128*4  = 32768 B
    float* bf  = (float*)(ws + 65536 + 32768);       // 128*4     = 512 B
    float* u   = (float*)(ws + 131072);              // N*128*4   = 25.6 MB

    // out accumulates the scatter-add -> must start at zero
    hipMemsetAsync(d_out, 0, (size_t)out_size * sizeof(float), stream);

    fuse_weights_kernel<<<(24704 + 255) / 256, 256, 0, stream>>>(
        Wx, bx, We, be, Wm, bm, Wxm, Wem, bf);

    node_gemm_kernel<<<(N + 31) / 32, 256, 0, stream>>>(x, Wxm, bf, u, N);

    edge_kernel<<<(E + 63) / 64, 512, 0, stream>>>(ea, ei, Wem, u, out, E);

    finalize_kernel<<<(out_size / 4 + 255) / 256, 256, 0, stream>>>(
        out, beta, out_size / 4);
}

// Round 3
// 1059.306 us; speedup vs baseline: 1.1916x; 1.1916x over previous
//
#include <hip/hip_runtime.h>

// N=50000, E=600000, IN_CH=128, EDGE_DIM=64, OUT_CH=128
// edge_index delivered as int32 (harness converts int64 -> int32).
//
// Structure:
//   fuse_weights: Wxm = Wx@Wm_top, Wem = We@Wm_bot, bf = folded biases
//   node_gemm:    u = x@Wxm + bf                       [N,128]
//   hist/scan/scatter: counting-sort edge ids by dst bucket (32 nodes/bucket)
//   edge_bucket:  per bucket: tile-GEMM ea@Wem, + u[src], leaky_relu,
//                 ds_add into LDS accum, final sigmoid()*relu(beta) store.
//                 -> ZERO global atomics (R2 showed 76.8M f32 atomics cost
//                    1.23 GB of 16B EA write-throughs and capped at 75G/s).

#define NB_SHIFT 5
#define BUCKET_NODES 32

// ---------------------------------------------------------------------------
__global__ void fuse_weights_kernel(const float* __restrict__ Wx,
                                    const float* __restrict__ bx,
                                    const float* __restrict__ We,
                                    const float* __restrict__ be,
                                    const float* __restrict__ Wm,
                                    const float* __restrict__ bm,
                                    float* __restrict__ Wxm,
                                    float* __restrict__ Wem,
                                    float* __restrict__ bf) {
    int idx = blockIdx.x * blockDim.x + threadIdx.x;
    if (idx < 128 * 128) {
        int r = idx >> 7, c = idx & 127;
        float acc = 0.f;
        #pragma unroll 8
        for (int j = 0; j < 128; ++j) acc += Wx[r * 128 + j] * Wm[j * 128 + c];
        Wxm[idx] = acc;
    } else if (idx < 128 * 128 + 64 * 128) {
        int t = idx - 128 * 128;
        int r = t >> 7, c = t & 127;
        float acc = 0.f;
        #pragma unroll 8
        for (int j = 0; j < 128; ++j) acc += We[r * 128 + j] * Wm[(128 + j) * 128 + c];
        Wem[t] = acc;
    } else if (idx < 128 * 128 + 64 * 128 + 128) {
        int c = idx - (128 * 128 + 64 * 128);
        float acc = bm[c];
        #pragma unroll 8
        for (int j = 0; j < 128; ++j)
            acc += bx[j] * Wm[j * 128 + c] + be[j] * Wm[(128 + j) * 128 + c];
        bf[c] = acc;
    }
}

// ---------------------------------------------------------------------------
// u[n][c] = sum_k x[n][k]*Wxm[k][c] + bf[c]
// ---------------------------------------------------------------------------
__global__ __launch_bounds__(256) void node_gemm_kernel(
        const float* __restrict__ x, const float* __restrict__ Wxm,
        const float* __restrict__ bf, float* __restrict__ u, int nNodes) {
    __shared__ __align__(16) float xs[32][128];   // 16 KB
    __shared__ __align__(16) float ws[64][128];   // 32 KB

    int tid = threadIdx.x;
    int n0 = blockIdx.x * 32;

    const float4* x4 = (const float4*)x;
    #pragma unroll
    for (int i = 0; i < 4; ++i) {
        int li = tid + i * 256;
        int r = li >> 5, c4 = li & 31;
        int n = n0 + r;
        float4 v = make_float4(0.f, 0.f, 0.f, 0.f);
        if (n < nNodes) v = x4[(size_t)n * 32 + c4];
        *((float4*)&xs[r][c4 * 4]) = v;
    }

    int cg = tid & 31, ig = tid >> 5;
    int c0 = cg * 4, i0 = ig * 4;
    float acc[4][4] = {};

    for (int kc = 0; kc < 2; ++kc) {
        __syncthreads();
        const float4* w4 = (const float4*)(Wxm + kc * 64 * 128);
        #pragma unroll
        for (int i = 0; i < 8; ++i) {
            int li = tid + i * 256;
            ((float4*)ws)[li] = w4[li];
        }
        __syncthreads();
        #pragma unroll 4
        for (int k = 0; k < 64; ++k) {
            float4 wv = *((const float4*)&ws[k][c0]);
            int kk = kc * 64 + k;
            float xv[4];
            xv[0] = xs[i0 + 0][kk];
            xv[1] = xs[i0 + 1][kk];
            xv[2] = xs[i0 + 2][kk];
            xv[3] = xs[i0 + 3][kk];
            #pragma unroll
            for (int a = 0; a < 4; ++a) {
                acc[a][0] += xv[a] * wv.x;
                acc[a][1] += xv[a] * wv.y;
                acc[a][2] += xv[a] * wv.z;
                acc[a][3] += xv[a] * wv.w;
            }
        }
    }

    float4 bfv = ((const float4*)bf)[cg];
    #pragma unroll
    for (int a = 0; a < 4; ++a) {
        int n = n0 + i0 + a;
        if (n < nNodes) {
            float4 o;
            o.x = acc[a][0] + bfv.x;
            o.y = acc[a][1] + bfv.y;
            o.z = acc[a][2] + bfv.z;
            o.w = acc[a][3] + bfv.w;
            *((float4*)(u + (size_t)n * 128 + c0)) = o;
        }
    }
}

// ---------------------------------------------------------------------------
// counting sort by destination bucket
// ---------------------------------------------------------------------------
__global__ void hist_kernel(const int* __restrict__ ei, int* __restrict__ cnt, int E) {
    int e = blockIdx.x * blockDim.x + threadIdx.x;
    if (e < E) atomicAdd(&cnt[ei[E + e] >> NB_SHIFT], 1);
}

// single block, 1024 threads; nb <= 2048
__global__ __launch_bounds__(1024) void scan_kernel(
        const int* __restrict__ cnt, int* __restrict__ start,
        int* __restrict__ cur, int nb, int E) {
    __shared__ int s[2048];
    int t = threadIdx.x;
    s[t]        = (t < nb)        ? cnt[t]        : 0;
    s[t + 1024] = (t + 1024 < nb) ? cnt[t + 1024] : 0;
    // Blelloch upsweep
    for (int d = 1; d < 2048; d <<= 1) {
        __syncthreads();
        int idx = (t + 1) * (d << 1) - 1;
        if (idx < 2048) s[idx] += s[idx - d];
    }
    __syncthreads();
    if (t == 0) s[2047] = 0;
    // downsweep -> exclusive prefix
    for (int d = 1024; d >= 1; d >>= 1) {
        __syncthreads();
        int idx = (t + 1) * (d << 1) - 1;
        if (idx < 2048) { int tmp = s[idx - d]; s[idx - d] = s[idx]; s[idx] += tmp; }
    }
    __syncthreads();
    if (t < nb)        { start[t] = s[t];               cur[t] = s[t]; }
    if (t + 1024 < nb) { start[t + 1024] = s[t + 1024]; cur[t + 1024] = s[t + 1024]; }
    if (t == 0) start[nb] = E;
}

__global__ void scatter_kernel(const int* __restrict__ ei, int* __restrict__ cur,
                               int* __restrict__ sorted, int E) {
    int e = blockIdx.x * blockDim.x + threadIdx.x;
    if (e < E) {
        int b = ei[E + e] >> NB_SHIFT;
        int pos = atomicAdd(&cur[b], 1);
        sorted[pos] = e;
    }
}

// ---------------------------------------------------------------------------
// per-bucket edge GEMM + LDS accumulate + fused finalize
// grid = nb buckets, 256 threads.
// LDS: wem 32K + accum 16K + eas 8K + ids 384B = ~56.4KB -> 2 blocks/CU.
// ---------------------------------------------------------------------------
__global__ __launch_bounds__(256) void edge_bucket_kernel(
        const float* __restrict__ ea, const int* __restrict__ ei,
        const float* __restrict__ Wem, const float* __restrict__ u,
        const int* __restrict__ start, const int* __restrict__ sorted,
        const float* __restrict__ beta, float* __restrict__ out,
        int E, int N) {
    __shared__ __align__(16) float wem[64][128];    // 32 KB
    __shared__ __align__(16) float accum[32][128];  // 16 KB
    __shared__ __align__(16) float eas[32][64];     //  8 KB
    __shared__ int ids[32], srcs[32], dstl[32];

    int tid = threadIdx.x;
    int b = blockIdx.x;
    int base = b << NB_SHIFT;

    // stage Wem (once) + zero accum
    #pragma unroll
    for (int i = 0; i < 8; ++i)
        ((float4*)wem)[tid + i * 256] = ((const float4*)Wem)[tid + i * 256];
    #pragma unroll
    for (int i = 0; i < 4; ++i)
        ((float4*)accum)[tid + i * 256] = make_float4(0.f, 0.f, 0.f, 0.f);

    int s0 = start[b], s1 = start[b + 1];

    int cg = tid & 31, ig = tid >> 5;
    int c0 = cg * 4, i0 = ig * 4;

    for (int t0 = s0; t0 < s1; t0 += 32) {
        int m = s1 - t0; if (m > 32) m = 32;
        __syncthreads();   // protects eas/ids reuse + initial staging
        if (tid < 32) {
            if (tid < m) {
                int e = sorted[t0 + tid];
                ids[tid]  = e;
                srcs[tid] = ei[e];
                dstl[tid] = ei[E + e] - base;
            }
        }
        __syncthreads();
        // gather edge_attr rows for this tile
        #pragma unroll
        for (int i = 0; i < 2; ++i) {
            int li = tid + i * 256;       // 0..511
            int r = li >> 4, c4 = li & 15;
            float4 v = make_float4(0.f, 0.f, 0.f, 0.f);
            if (r < m) v = ((const float4*)ea)[(size_t)ids[r] * 16 + c4];
            *((float4*)&eas[r][c4 * 4]) = v;
        }
        __syncthreads();

        float acc[4][4] = {};
        #pragma unroll 4
        for (int k = 0; k < 64; ++k) {
            float4 wv = *((const float4*)&wem[k][c0]);
            float xv[4];
            xv[0] = eas[i0 + 0][k];
            xv[1] = eas[i0 + 1][k];
            xv[2] = eas[i0 + 2][k];
            xv[3] = eas[i0 + 3][k];
            #pragma unroll
            for (int a = 0; a < 4; ++a) {
                acc[a][0] += xv[a] * wv.x;
                acc[a][1] += xv[a] * wv.y;
                acc[a][2] += xv[a] * wv.z;
                acc[a][3] += xv[a] * wv.w;
            }
        }

        #pragma unroll
        for (int a = 0; a < 4; ++a) {
            int li = i0 + a;
            if (li < m) {
                float4 uv = ((const float4*)u)[(size_t)srcs[li] * 32 + cg];
                float m0 = acc[a][0] + uv.x;
                float m1 = acc[a][1] + uv.y;
                float m2 = acc[a][2] + uv.z;
                float m3 = acc[a][3] + uv.w;
                m0 = m0 > 0.f ? m0 : 0.01f * m0;
                m1 = m1 > 0.f ? m1 : 0.01f * m1;
                m2 = m2 > 0.f ? m2 : 0.01f * m2;
                m3 = m3 > 0.f ? m3 : 0.01f * m3;
                int dl = dstl[li];
                atomicAdd(&accum[dl][c0 + 0], m0);
                atomicAdd(&accum[dl][c0 + 1], m1);
                atomicAdd(&accum[dl][c0 + 2], m2);
                atomicAdd(&accum[dl][c0 + 3], m3);
            }
        }
    }
    __syncthreads();

    float rb = beta[0];
    rb = rb > 0.f ? rb : 0.f;
    #pragma unroll
    for (int i = 0; i < 4; ++i) {
        int li = tid + i * 256;
        int r = li >> 5, c4 = li & 31;
        int n = base + r;
        if (n < N) {
            float4 v = *((float4*)&accum[r][c4 * 4]);
            v.x = rb / (1.f + __expf(-v.x));
            v.y = rb / (1.f + __expf(-v.y));
            v.z = rb / (1.f + __expf(-v.z));
            v.w = rb / (1.f + __expf(-v.w));
            ((float4*)out)[(size_t)n * 32 + c4] = v;
        }
    }
}

// ---------------------------------------------------------------------------
extern "C" void kernel_launch(void* const* d_in, const int* in_sizes, int n_in,
                              void* d_out, int out_size, void* d_ws, size_t ws_size,
                              hipStream_t stream) {
    const float* x    = (const float*)d_in[0];
    const int*   ei   = (const int*)d_in[1];
    const float* ea   = (const float*)d_in[2];
    const float* Wx   = (const float*)d_in[3];
    const float* bx   = (const float*)d_in[4];
    const float* We   = (const float*)d_in[5];
    const float* be   = (const float*)d_in[6];
    const float* Wm   = (const float*)d_in[7];
    const float* bm   = (const float*)d_in[8];
    const float* beta = (const float*)d_in[9];

    int N = in_sizes[0] / 128;   // 50000
    int E = in_sizes[2] / 64;    // 600000
    int nb = (N + BUCKET_NODES - 1) >> NB_SHIFT;   // 1563

    float* out = (float*)d_out;

    // workspace layout (16B-aligned)
    char*  ws  = (char*)d_ws;
    float* Wxm = (float*)(ws);                         // 64 KB
    float* Wem = (float*)(ws + 65536);                 // 32 KB
    float* bf  = (float*)(ws + 65536 + 32768);         // 512 B
    float* u   = (float*)(ws + 131072);                // N*128*4 = 25.6 MB
    char*  p   = ws + 131072 + (size_t)N * 128 * 4;
    int* cnt    = (int*)(p);                           // nb ints
    int* startb = (int*)(p + 8192);                    // nb+1 ints
    int* cur    = (int*)(p + 16384);                   // nb ints
    int* sorted = (int*)(p + 24576);                   // E ints = 2.4 MB

    hipMemsetAsync(cnt, 0, (size_t)nb * sizeof(int), stream);

    fuse_weights_kernel<<<(24704 + 255) / 256, 256, 0, stream>>>(
        Wx, bx, We, be, Wm, bm, Wxm, Wem, bf);

    node_gemm_kernel<<<(N + 31) / 32, 256, 0, stream>>>(x, Wxm, bf, u, N);

    hist_kernel<<<(E + 255) / 256, 256, 0, stream>>>(ei, cnt, E);
    scan_kernel<<<1, 1024, 0, stream>>>(cnt, startb, cur, nb, E);
    scatter_kernel<<<(E + 255) / 256, 256, 0, stream>>>(ei, cur, sorted, E);

    edge_bucket_kernel<<<nb, 256, 0, stream>>>(
        ea, ei, Wem, u, startb, sorted, beta, out, E, N);
}

// Round 4
// 917.239 us; speedup vs baseline: 1.3761x; 1.1549x over previous
//
#include <hip/hip_runtime.h>

// N=50000, E=600000, IN_CH=128, EDGE_DIM=64, OUT_CH=128
// edge_index delivered as int32.
//
// R4: edge kernel moved to bf16 MFMA (16x16x32), wemT/eas staged k-major bf16
// with rows padded to 72 elems (kills stride-128B bank conflicts), register
// prefetch pipeline for the ea gather, direct sorted[] index loads (no serial
// tid<32 section), LDS 40.2KB -> 4 blocks/CU.

#define NB_SHIFT 5
#define BUCKET_NODES 32

typedef __bf16 bf16x8 __attribute__((ext_vector_type(8)));
typedef float  f32x4  __attribute__((ext_vector_type(4)));
typedef unsigned short ushort_t;
typedef unsigned int   uint_t;

__device__ __forceinline__ ushort_t f2b(float f) {   // RNE f32->bf16
    uint_t u = __float_as_uint(f);
    u += 0x7FFF + ((u >> 16) & 1);
    return (ushort_t)(u >> 16);
}
__device__ __forceinline__ uint_t pack2(ushort_t a, ushort_t b) {
    return (uint_t)a | ((uint_t)b << 16);
}

// ---------------------------------------------------------------------------
// K1: fold weights. Wxm f32 [128][128]; WemT bf16 k-major [128 ch][64 k]; bf.
// ---------------------------------------------------------------------------
__global__ void fuse_weights_kernel(const float* __restrict__ Wx,
                                    const float* __restrict__ bx,
                                    const float* __restrict__ We,
                                    const float* __restrict__ be,
                                    const float* __restrict__ Wm,
                                    const float* __restrict__ bm,
                                    float* __restrict__ Wxm,
                                    ushort_t* __restrict__ WemT16,
                                    float* __restrict__ bf) {
    int idx = blockIdx.x * blockDim.x + threadIdx.x;
    if (idx < 128 * 128) {
        int r = idx >> 7, c = idx & 127;
        float acc = 0.f;
        #pragma unroll 8
        for (int j = 0; j < 128; ++j) acc += Wx[r * 128 + j] * Wm[j * 128 + c];
        Wxm[idx] = acc;
    } else if (idx < 128 * 128 + 64 * 128) {
        int t = idx - 128 * 128;
        int r = t >> 7, c = t & 127;          // r = k (<64), c = ch (<128)
        float acc = 0.f;
        #pragma unroll 8
        for (int j = 0; j < 128; ++j) acc += We[r * 128 + j] * Wm[(128 + j) * 128 + c];
        WemT16[c * 64 + r] = f2b(acc);        // k-major, bf16
    } else if (idx < 128 * 128 + 64 * 128 + 128) {
        int c = idx - (128 * 128 + 64 * 128);
        float acc = bm[c];
        #pragma unroll 8
        for (int j = 0; j < 128; ++j)
            acc += bx[j] * Wm[j * 128 + c] + be[j] * Wm[(128 + j) * 128 + c];
        bf[c] = acc;
    }
}

// ---------------------------------------------------------------------------
// K2: u = x @ Wxm + bf   (f32 tile GEMM, unchanged from R3)
// ---------------------------------------------------------------------------
__global__ __launch_bounds__(256) void node_gemm_kernel(
        const float* __restrict__ x, const float* __restrict__ Wxm,
        const float* __restrict__ bf, float* __restrict__ u, int nNodes) {
    __shared__ __align__(16) float xs[32][128];
    __shared__ __align__(16) float ws[64][128];

    int tid = threadIdx.x;
    int n0 = blockIdx.x * 32;

    const float4* x4 = (const float4*)x;
    #pragma unroll
    for (int i = 0; i < 4; ++i) {
        int li = tid + i * 256;
        int r = li >> 5, c4 = li & 31;
        int n = n0 + r;
        float4 v = make_float4(0.f, 0.f, 0.f, 0.f);
        if (n < nNodes) v = x4[(size_t)n * 32 + c4];
        *((float4*)&xs[r][c4 * 4]) = v;
    }

    int cg = tid & 31, ig = tid >> 5;
    int c0 = cg * 4, i0 = ig * 4;
    float acc[4][4] = {};

    for (int kc = 0; kc < 2; ++kc) {
        __syncthreads();
        const float4* w4 = (const float4*)(Wxm + kc * 64 * 128);
        #pragma unroll
        for (int i = 0; i < 8; ++i) {
            int li = tid + i * 256;
            ((float4*)ws)[li] = w4[li];
        }
        __syncthreads();
        #pragma unroll 4
        for (int k = 0; k < 64; ++k) {
            float4 wv = *((const float4*)&ws[k][c0]);
            int kk = kc * 64 + k;
            float xv[4];
            xv[0] = xs[i0 + 0][kk];
            xv[1] = xs[i0 + 1][kk];
            xv[2] = xs[i0 + 2][kk];
            xv[3] = xs[i0 + 3][kk];
            #pragma unroll
            for (int a = 0; a < 4; ++a) {
                acc[a][0] += xv[a] * wv.x;
                acc[a][1] += xv[a] * wv.y;
                acc[a][2] += xv[a] * wv.z;
                acc[a][3] += xv[a] * wv.w;
            }
        }
    }

    float4 bfv = ((const float4*)bf)[cg];
    #pragma unroll
    for (int a = 0; a < 4; ++a) {
        int n = n0 + i0 + a;
        if (n < nNodes) {
            float4 o;
            o.x = acc[a][0] + bfv.x;
            o.y = acc[a][1] + bfv.y;
            o.z = acc[a][2] + bfv.z;
            o.w = acc[a][3] + bfv.w;
            *((float4*)(u + (size_t)n * 128 + c0)) = o;
        }
    }
}

// ---------------------------------------------------------------------------
// counting sort by destination bucket (unchanged)
// ---------------------------------------------------------------------------
__global__ void hist_kernel(const int* __restrict__ ei, int* __restrict__ cnt, int E) {
    int e = blockIdx.x * blockDim.x + threadIdx.x;
    if (e < E) atomicAdd(&cnt[ei[E + e] >> NB_SHIFT], 1);
}

__global__ __launch_bounds__(1024) void scan_kernel(
        const int* __restrict__ cnt, int* __restrict__ start,
        int* __restrict__ cur, int nb, int E) {
    __shared__ int s[2048];
    int t = threadIdx.x;
    s[t]        = (t < nb)        ? cnt[t]        : 0;
    s[t + 1024] = (t + 1024 < nb) ? cnt[t + 1024] : 0;
    for (int d = 1; d < 2048; d <<= 1) {
        __syncthreads();
        int idx = (t + 1) * (d << 1) - 1;
        if (idx < 2048) s[idx] += s[idx - d];
    }
    __syncthreads();
    if (t == 0) s[2047] = 0;
    for (int d = 1024; d >= 1; d >>= 1) {
        __syncthreads();
        int idx = (t + 1) * (d << 1) - 1;
        if (idx < 2048) { int tmp = s[idx - d]; s[idx - d] = s[idx]; s[idx] += tmp; }
    }
    __syncthreads();
    if (t < nb)        { start[t] = s[t];               cur[t] = s[t]; }
    if (t + 1024 < nb) { start[t + 1024] = s[t + 1024]; cur[t + 1024] = s[t + 1024]; }
    if (t == 0) start[nb] = E;
}

__global__ void scatter_kernel(const int* __restrict__ ei, int* __restrict__ cur,
                               int* __restrict__ sorted, int E) {
    int e = blockIdx.x * blockDim.x + threadIdx.x;
    if (e < E) {
        int b = ei[E + e] >> NB_SHIFT;
        int pos = atomicAdd(&cur[b], 1);
        sorted[pos] = e;
    }
}

// ---------------------------------------------------------------------------
// K3: per-bucket MFMA edge GEMM + LDS accumulate + fused finalize.
// grid = nb buckets, 256 threads (4 waves).
// Wave w: edge-subtile (w&1)*16, channel half (w>>1)*64.
// LDS: wemT 18432 + eas 4608 + accum 16896 + idx 256 = 40192 B -> 4 blocks/CU.
// ---------------------------------------------------------------------------
__global__ __launch_bounds__(256, 4) void edge_bucket_kernel(
        const float* __restrict__ ea, const int* __restrict__ ei,
        const ushort_t* __restrict__ WemT16, const float* __restrict__ u,
        const int* __restrict__ start, const int* __restrict__ sorted,
        const float* __restrict__ beta, float* __restrict__ out,
        int E, int N) {
    __shared__ __align__(16) ushort_t wemT[128 * 72];   // [ch][k] padded
    __shared__ __align__(16) ushort_t eas[32 * 72];     // [edge][k] padded
    __shared__ __align__(16) float accum[32 * 132];     // [node][ch] padded
    __shared__ int srcs[32], dstl[32];

    int tid = threadIdx.x;
    int b = blockIdx.x;
    int base = b << NB_SHIFT;

    // stage WemT: 128 rows x 64 bf16 -> padded rows of 72
    #pragma unroll
    for (int i = 0; i < 4; ++i) {
        int li = tid + i * 256;            // 0..1023
        int row = li >> 3, seg = li & 7;
        *((uint4*)&wemT[row * 72 + seg * 8]) =
            *((const uint4*)&WemT16[row * 64 + seg * 8]);
    }
    // zero accum
    for (int li = tid; li < 32 * 132; li += 256) accum[li] = 0.f;

    int s0 = start[b], s1 = start[b + 1];
    int tiles = (s1 - s0 + 31) >> 5;

    const float4* ea4 = (const float4*)ea;
    int r8 = tid >> 3, c8 = tid & 7;       // gather role: row, k-segment

    int lane = tid & 63, wv = tid >> 6;
    int eSub = wv & 1, chBase = (wv >> 1) << 6;
    int l15 = lane & 15, quad = lane >> 4;
    int rbase = eSub * 16 + (quad << 2);

    // prefetch tile 0 ea rows into registers
    float4 pf0, pf1;
    {
        int m0 = s1 - s0; if (m0 > 32) m0 = 32;
        if (r8 < m0) {
            int e = sorted[s0 + r8];
            pf0 = ea4[(size_t)e * 16 + c8 * 2];
            pf1 = ea4[(size_t)e * 16 + c8 * 2 + 1];
        }
    }

    for (int tt = 0; tt < tiles; ++tt) {
        int t0 = s0 + (tt << 5);
        int m = s1 - t0; if (m > 32) m = 32;

        __syncthreads();   // previous tile's eas/srcs reads complete

        // stage current tile (bf16 convert), zero tail rows
        {
            uint4 w = make_uint4(0u, 0u, 0u, 0u);
            if (r8 < m) {
                w.x = pack2(f2b(pf0.x), f2b(pf0.y));
                w.y = pack2(f2b(pf0.z), f2b(pf0.w));
                w.z = pack2(f2b(pf1.x), f2b(pf1.y));
                w.w = pack2(f2b(pf1.z), f2b(pf1.w));
            }
            *((uint4*)&eas[r8 * 72 + c8 * 8]) = w;
        }
        // stage src/dst indices (parallel, no serial wave)
        if (tid < 64) {
            int lr = tid & 31;
            if (lr < m) {
                int e2 = sorted[t0 + lr];
                if (tid < 32) srcs[lr] = ei[e2];
                else          dstl[lr] = ei[E + e2] - base;
            }
        }
        // prefetch NEXT tile's ea rows (overlaps MFMA below)
        {
            int t0n = t0 + 32;
            if (t0n < s1) {
                int mn = s1 - t0n;
                if (r8 < mn) {
                    int e = sorted[t0n + r8];
                    pf0 = ea4[(size_t)e * 16 + c8 * 2];
                    pf1 = ea4[(size_t)e * 16 + c8 * 2 + 1];
                }
            }
        }
        __syncthreads();   // eas + srcs/dstl ready

        // prefetch u rows for epilogue (issued before MFMA)
        float uvv[16];
        int   dr[4];
        #pragma unroll
        for (int r = 0; r < 4; ++r) {
            int row = rbase + r;
            if (row < m) {
                int s = srcs[row];
                dr[r] = dstl[row];
                #pragma unroll
                for (int ct = 0; ct < 4; ++ct)
                    uvv[ct * 4 + r] = u[(size_t)s * 128 + chBase + (ct << 4) + l15];
            }
        }

        // MFMA: 16 edges x 64 ch per wave, K=64
        f32x4 acc[4] = {{0.f,0.f,0.f,0.f},{0.f,0.f,0.f,0.f},
                        {0.f,0.f,0.f,0.f},{0.f,0.f,0.f,0.f}};
        #pragma unroll
        for (int kk = 0; kk < 2; ++kk) {
            int k = (kk << 5) + (quad << 3);
            bf16x8 a = __builtin_bit_cast(bf16x8,
                *((const uint4*)&eas[(eSub * 16 + l15) * 72 + k]));
            #pragma unroll
            for (int ct = 0; ct < 4; ++ct) {
                bf16x8 bb = __builtin_bit_cast(bf16x8,
                    *((const uint4*)&wemT[(chBase + (ct << 4) + l15) * 72 + k]));
                acc[ct] = __builtin_amdgcn_mfma_f32_16x16x32_bf16(a, bb, acc[ct], 0, 0, 0);
            }
        }

        // epilogue: + u[src], leaky_relu, LDS atomic accumulate
        #pragma unroll
        for (int r = 0; r < 4; ++r) {
            int row = rbase + r;
            if (row < m) {
                #pragma unroll
                for (int ct = 0; ct < 4; ++ct) {
                    float msg = acc[ct][r] + uvv[ct * 4 + r];
                    msg = msg > 0.f ? msg : 0.01f * msg;
                    atomicAdd(&accum[dr[r] * 132 + chBase + (ct << 4) + l15], msg);
                }
            }
        }
    }
    __syncthreads();

    // fused finalize: sigmoid(agg) * relu(beta)
    float rb = beta[0];
    rb = rb > 0.f ? rb : 0.f;
    #pragma unroll
    for (int i = 0; i < 4; ++i) {
        int li = tid + i * 256;
        int r = li >> 5, c4 = li & 31;
        int n = base + r;
        if (n < N) {
            float4 v = *((float4*)&accum[r * 132 + c4 * 4]);
            v.x = rb / (1.f + __expf(-v.x));
            v.y = rb / (1.f + __expf(-v.y));
            v.z = rb / (1.f + __expf(-v.z));
            v.w = rb / (1.f + __expf(-v.w));
            ((float4*)out)[(size_t)n * 32 + c4] = v;
        }
    }
}

// ---------------------------------------------------------------------------
extern "C" void kernel_launch(void* const* d_in, const int* in_sizes, int n_in,
                              void* d_out, int out_size, void* d_ws, size_t ws_size,
                              hipStream_t stream) {
    const float* x    = (const float*)d_in[0];
    const int*   ei   = (const int*)d_in[1];
    const float* ea   = (const float*)d_in[2];
    const float* Wx   = (const float*)d_in[3];
    const float* bx   = (const float*)d_in[4];
    const float* We   = (const float*)d_in[5];
    const float* be   = (const float*)d_in[6];
    const float* Wm   = (const float*)d_in[7];
    const float* bm   = (const float*)d_in[8];
    const float* beta = (const float*)d_in[9];

    int N = in_sizes[0] / 128;   // 50000
    int E = in_sizes[2] / 64;    // 600000
    int nb = (N + BUCKET_NODES - 1) >> NB_SHIFT;   // 1563

    float* out = (float*)d_out;

    // workspace layout (16B-aligned)
    char*     ws      = (char*)d_ws;
    float*    Wxm     = (float*)(ws);                      // 64 KB
    ushort_t* WemT16  = (ushort_t*)(ws + 65536);           // 16 KB
    float*    bf      = (float*)(ws + 65536 + 16384);      // 512 B
    float*    u       = (float*)(ws + 131072);             // 25.6 MB
    char*     p       = ws + 131072 + (size_t)N * 128 * 4;
    int* cnt    = (int*)(p);
    int* startb = (int*)(p + 8192);
    int* cur    = (int*)(p + 16384);
    int* sorted = (int*)(p + 24576);                       // E ints

    hipMemsetAsync(cnt, 0, (size_t)nb * sizeof(int), stream);

    fuse_weights_kernel<<<(24704 + 255) / 256, 256, 0, stream>>>(
        Wx, bx, We, be, Wm, bm, Wxm, WemT16, bf);

    node_gemm_kernel<<<(N + 31) / 32, 256, 0, stream>>>(x, Wxm, bf, u, N);

    hist_kernel<<<(E + 255) / 256, 256, 0, stream>>>(ei, cnt, E);
    scan_kernel<<<1, 1024, 0, stream>>>(cnt, startb, cur, nb, E);
    scatter_kernel<<<(E + 255) / 256, 256, 0, stream>>>(ei, cur, sorted, E);

    edge_bucket_kernel<<<nb, 256, 0, stream>>>(
        ea, ei, WemT16, u, startb, sorted, beta, out, E, N);
}